// Round 7
// baseline (1015.195 us; speedup 1.0000x reference)
//
#include <hip/hip_runtime.h>
#include <cmath>
#include <cstddef>

#define N_NODES 50000
#define N_PAD   50048
#define E_EDGES 640000
#define HDIM 128
#define COUT 64
#define NLAYERS 16
#define ALPHA_C 0.1f
#define LAMDA_C 0.5f
#define SCAN_BLKS 196   // ceil(50000/256)
#define SLS ((size_t)N_PAD * 64)   // slice stride (elements)

typedef __attribute__((ext_vector_type(8))) short short8;
typedef __attribute__((ext_vector_type(4))) float f32x4;

__device__ __forceinline__ float bf2f(ushort u) {
    union { unsigned u; float f; } x; x.u = ((unsigned)u) << 16; return x.f;
}
__device__ __forceinline__ ushort f2bf(float f) {
    union { float f; unsigned u; } x; x.f = f;
    unsigned r = x.u + 0x7FFFu + ((x.u >> 16) & 1u);
    return (ushort)(r >> 16);
}

// ---------------- graph setup ----------------

__global__ __launch_bounds__(256) void k_init(float* deg, int* cnt) {
    int i = blockIdx.x * 256 + threadIdx.x;
    if (i < N_NODES) { deg[i] = 1.0f; cnt[i] = 0; }
}

// 4 edges/thread; cnt atomicAdd return value = intra-bucket rank (kills scatter atomics)
__global__ __launch_bounds__(256) void k_edge(const int* __restrict__ ei,
                                              const float* __restrict__ ew,
                                              float* deg, int* cnt,
                                              int* __restrict__ rank) {
    int t = blockIdx.x * 256 + threadIdx.x;
    int e0 = t * 4;
    if (e0 >= E_EDGES) return;
    int4 r = *(const int4*)&ei[e0];
    int4 c = *(const int4*)&ei[E_EDGES + e0];
    float4 w = *(const float4*)&ew[e0];
    atomicAdd(&deg[r.x], w.x);
    atomicAdd(&deg[r.y], w.y);
    atomicAdd(&deg[r.z], w.z);
    atomicAdd(&deg[r.w], w.w);
    int4 rk;
    rk.x = atomicAdd(&cnt[c.x], 1);
    rk.y = atomicAdd(&cnt[c.y], 1);
    rk.z = atomicAdd(&cnt[c.z], 1);
    rk.w = atomicAdd(&cnt[c.w], 1);
    *(int4*)&rank[e0] = rk;
}

__global__ __launch_bounds__(256) void k_dinv(float* deg) {
    int i = blockIdx.x * 256 + threadIdx.x;
    if (i < N_NODES) deg[i] = 1.0f / sqrtf(deg[i]);
}

__global__ __launch_bounds__(256) void k_scan1(const int* __restrict__ cnt,
                                               int* ptrTmp, int* bsum) {
    __shared__ int s[256];
    int t = threadIdx.x;
    int i = blockIdx.x * 256 + t;
    int v = (i < N_NODES) ? cnt[i] : 0;
    s[t] = v; __syncthreads();
    for (int off = 1; off < 256; off <<= 1) {
        int x = s[t]; int y = (t >= off) ? s[t - off] : 0;
        __syncthreads();
        s[t] = x + y; __syncthreads();
    }
    if (i < N_NODES) ptrTmp[i] = s[t] - v;
    if (t == 255) bsum[blockIdx.x] = s[255];
}

__global__ __launch_bounds__(256) void k_scan2(const int* __restrict__ bsum, int* boff) {
    __shared__ int s[256];
    int t = threadIdx.x;
    int v = (t < SCAN_BLKS) ? bsum[t] : 0;
    s[t] = v; __syncthreads();
    for (int off = 1; off < 256; off <<= 1) {
        int x = s[t]; int y = (t >= off) ? s[t - off] : 0;
        __syncthreads();
        s[t] = x + y; __syncthreads();
    }
    if (t < SCAN_BLKS) boff[t] = s[t] - v;
}

__global__ __launch_bounds__(256) void k_scan3(const int* __restrict__ ptrTmp,
                                               const int* __restrict__ boff, int* ptr) {
    int i = blockIdx.x * 256 + threadIdx.x;
    if (i < N_NODES) ptr[i] = ptrTmp[i] + boff[blockIdx.x];
    if (i == 0) ptr[N_NODES] = E_EDGES;
}

// atomic-free scatter: pos = ptr[c] + rank[e]; meta packed (row<<16 | bf16(norm))
__global__ __launch_bounds__(256) void k_scatter(const int* __restrict__ ei,
                                                 const float* __restrict__ ew,
                                                 const float* __restrict__ dinv,
                                                 const int* __restrict__ ptr,
                                                 const int* __restrict__ rank,
                                                 unsigned* __restrict__ spacku) {
    int t = blockIdx.x * 256 + threadIdx.x;
    int e0 = t * 4;
    if (e0 >= E_EDGES) return;
    int4 r = *(const int4*)&ei[e0];
    int4 c = *(const int4*)&ei[E_EDGES + e0];
    float4 w = *(const float4*)&ew[e0];
    int4 rk = *(const int4*)&rank[e0];
#pragma unroll
    for (int j = 0; j < 4; ++j) {
        int rr = (j == 0) ? r.x : (j == 1) ? r.y : (j == 2) ? r.z : r.w;
        int cc = (j == 0) ? c.x : (j == 1) ? c.y : (j == 2) ? c.z : c.w;
        float wwv = (j == 0) ? w.x : (j == 1) ? w.y : (j == 2) ? w.z : w.w;
        int rkj = (j == 0) ? rk.x : (j == 1) ? rk.y : (j == 2) ? rk.z : rk.w;
        int pos = ptr[cc] + rkj;
        float nm = dinv[rr] * wwv * dinv[cc];
        spacku[pos] = ((unsigned)rr << 16) | (unsigned)f2bf(nm);
    }
}

// ---------------- weight convert + transpose + residual fold ----------------

__global__ __launch_bounds__(256) void k_convert_w(
    const float* __restrict__ w_in, const float* __restrict__ ws1,
    const float* __restrict__ ws2, const float* __restrict__ w_out,
    ushort* wt_in, ushort* wt1, ushort* wt2, ushort* wt_out) {
    __shared__ float tile[128][129];
    int b = blockIdx.x;
    const float* src; ushort* dst; int R = 128, C = 128;
    float scale = 1.f, diag = 0.f;
    if (b == 0) { src = w_in; dst = wt_in; }
    else if (b <= 16) {
        int i = b - 1;
        float beta = logf(LAMDA_C / (float)(i + 1) + 1.0f);
        scale = beta; diag = (1.f - beta) * (1.f - ALPHA_C);
        src = ws1 + (size_t)i * 16384; dst = wt1 + (size_t)i * 16384;
    } else if (b <= 32) {
        int i = b - 17;
        float beta = logf(LAMDA_C / (float)(i + 1) + 1.0f);
        scale = beta; diag = (1.f - beta) * ALPHA_C;
        src = ws2 + (size_t)i * 16384; dst = wt2 + (size_t)i * 16384;
    } else { src = w_out; dst = wt_out; C = 64; }
    for (int idx = threadIdx.x; idx < R * C; idx += 256) {
        int k = idx / C, n = idx % C;
        tile[k][n] = src[idx] * scale + ((k == n) ? diag : 0.f);
    }
    __syncthreads();
    for (int idx = threadIdx.x; idx < R * C; idx += 256) {
        int n = idx / R, k = idx % R;
        dst[idx] = f2bf(tile[k][n]);
    }
}

// ---------------- x convert (f32 -> bf16, zero-pad rows) ----------------

__global__ __launch_bounds__(256) void k_convert_x(const float* __restrict__ x,
                                                   ushort* __restrict__ xb) {
    int c8 = blockIdx.x * 256 + threadIdx.x;
    if (c8 >= N_PAD * (HDIM / 8)) return;
    int row = c8 / (HDIM / 8);
    short8 o;
    if (row < N_NODES) {
        const float4 f0 = *(const float4*)&x[(size_t)c8 * 8];
        const float4 f1 = *(const float4*)&x[(size_t)c8 * 8 + 4];
        o[0] = (short)f2bf(f0.x); o[1] = (short)f2bf(f0.y);
        o[2] = (short)f2bf(f0.z); o[3] = (short)f2bf(f0.w);
        o[4] = (short)f2bf(f1.x); o[5] = (short)f2bf(f1.y);
        o[6] = (short)f2bf(f1.z); o[7] = (short)f2bf(f1.w);
    } else {
        o = (short8){0, 0, 0, 0, 0, 0, 0, 0};
    }
    *(short8*)&xb[(size_t)c8 * 8] = o;
}

// ---------------- input GEMM: h(sliced) = h0(linear) = relu(xb @ W + bias) ----------------

__global__ __launch_bounds__(256) void k_gemm_in(
    const ushort* __restrict__ A, const ushort* __restrict__ W,
    const float* __restrict__ bias, ushort* __restrict__ Hs, ushort* __restrict__ H0) {
    const int tid = threadIdx.x;
    const int wid = tid >> 6, l = tid & 63;
    const int wm = wid >> 1, wn = wid & 1;
    const int lr = l & 15, lk = l >> 4;
    const int row0 = blockIdx.x * 128 + wm * 64;
    const int col0 = wn * 64;

    short8 a[4][4], b[4][4];
#pragma unroll
    for (int m = 0; m < 4; ++m)
#pragma unroll
        for (int k = 0; k < 4; ++k)
            a[m][k] = *(const short8*)&A[(size_t)(row0 + m * 16 + lr) * HDIM + k * 32 + lk * 8];
#pragma unroll
    for (int n = 0; n < 4; ++n)
#pragma unroll
        for (int k = 0; k < 4; ++k)
            b[n][k] = *(const short8*)&W[(size_t)(col0 + n * 16 + lr) * HDIM + k * 32 + lk * 8];

    f32x4 acc[4][4];
#pragma unroll
    for (int m = 0; m < 4; ++m)
#pragma unroll
        for (int n = 0; n < 4; ++n) acc[m][n] = (f32x4){0.f, 0.f, 0.f, 0.f};
#pragma unroll
    for (int k = 0; k < 4; ++k)
#pragma unroll
        for (int m = 0; m < 4; ++m)
#pragma unroll
            for (int n = 0; n < 4; ++n)
                acc[m][n] = __builtin_amdgcn_mfma_f32_16x16x32_bf16(a[m][k], b[n][k], acc[m][n], 0, 0, 0);

    float bv[4];
#pragma unroll
    for (int n = 0; n < 4; ++n) bv[n] = bias[col0 + n * 16 + lr];
#pragma unroll
    for (int m = 0; m < 4; ++m) {
        const int rb = row0 + m * 16 + lk * 4;
#pragma unroll
        for (int j = 0; j < 4; ++j) {
            const int row = rb + j;
#pragma unroll
            for (int n = 0; n < 4; ++n) {
                float v = fmaxf(acc[m][n][j] + bv[n], 0.f);
                ushort u = f2bf(v);
                Hs[(size_t)wn * SLS + (size_t)row * 64 + n * 16 + lr] = u;
                H0[(size_t)row * HDIM + col0 + n * 16 + lr] = u;
            }
        }
    }
}

// ---------------- aggregation: sliced (L2-local) + round-6 wave shape ----------------
// wave = (node, slice); 16 lanes x ushort4 = 64 dims; 4 edges in flight, 2x unroll.
// slice = blockIdx&1: round-robin block->XCD pins each 6.4MB slice to 4 XCDs.

__global__ __launch_bounds__(256) void k_aggregate(
    const ushort* __restrict__ h, const float* __restrict__ dinv,
    const int* __restrict__ ptr, const unsigned* __restrict__ spacku,
    ushort* __restrict__ agg) {
    const int blk = blockIdx.x;
    const int slice = blk & 1;
    const int v = (blk >> 1) * 4 + (threadIdx.x >> 6);
    const int l = threadIdx.x & 63;
    const int q = l >> 4, i = l & 15;
    if (v >= N_NODES) return;
    const ushort* __restrict__ hs = h + (size_t)slice * SLS;
    const int beg = ptr[v], end = ptr[v + 1];

    float acc[4];
#pragma unroll
    for (int d = 0; d < 4; ++d) acc[d] = 0.f;

    for (int base = beg; base < end; base += 64) {
        const int cnt = min(64, end - base);
        unsigned meta = 0;
        if (base + l < end) meta = spacku[base + l];
        for (int j = 0; j < cnt; j += 8) {
            unsigned mu0 = (unsigned)__shfl((int)meta, j + q);
            unsigned mu1 = (unsigned)__shfl((int)meta, j + 4 + q);
            int rr0 = (int)(mu0 >> 16);
            int rr1 = (int)(mu1 >> 16);
            ushort4 sv0 = *(const ushort4*)&hs[(size_t)rr0 * 64 + i * 4];
            ushort4 sv1 = *(const ushort4*)&hs[(size_t)rr1 * 64 + i * 4];
            float nn0 = bf2f((ushort)(mu0 & 0xFFFFu));
            float nn1 = bf2f((ushort)(mu1 & 0xFFFFu));
            acc[0] = fmaf(nn0, bf2f(sv0.x), acc[0]);
            acc[1] = fmaf(nn0, bf2f(sv0.y), acc[1]);
            acc[2] = fmaf(nn0, bf2f(sv0.z), acc[2]);
            acc[3] = fmaf(nn0, bf2f(sv0.w), acc[3]);
            acc[0] = fmaf(nn1, bf2f(sv1.x), acc[0]);
            acc[1] = fmaf(nn1, bf2f(sv1.y), acc[1]);
            acc[2] = fmaf(nn1, bf2f(sv1.z), acc[2]);
            acc[3] = fmaf(nn1, bf2f(sv1.w), acc[3]);
        }
    }
#pragma unroll
    for (int d = 0; d < 4; ++d) {
        acc[d] += __shfl_xor(acc[d], 16);
        acc[d] += __shfl_xor(acc[d], 32);
    }
    if (q == 0) {
        const float dv = dinv[v];
        const float dv2 = dv * dv;
        ushort4 s0 = *(const ushort4*)&hs[(size_t)v * 64 + i * 4];
        ushort4 o;
        o.x = f2bf(acc[0] + dv2 * bf2f(s0.x));
        o.y = f2bf(acc[1] + dv2 * bf2f(s0.y));
        o.z = f2bf(acc[2] + dv2 * bf2f(s0.z));
        o.w = f2bf(acc[3] + dv2 * bf2f(s0.w));
        *(ushort4*)&agg[(size_t)slice * SLS + (size_t)v * 64 + i * 4] = o;
    }
}

// ---------------- layer GEMM: h = relu(agg_h @ W1' + h0 @ W2') ----------------
// AGG sliced, H0 linear, H out sliced; residuals folded into W'.

__global__ __launch_bounds__(256) void k_gemm_layer(
    const ushort* __restrict__ AGG, const ushort* __restrict__ H0,
    const ushort* __restrict__ W1, const ushort* __restrict__ W2,
    ushort* __restrict__ H) {
    const int tid = threadIdx.x;
    const int wid = tid >> 6, l = tid & 63;
    const int wm = wid >> 1, wn = wid & 1;
    const int lr = l & 15, lk = l >> 4;
    const int row0 = blockIdx.x * 128 + wm * 64;
    const int col0 = wn * 64;

    f32x4 acc[4][4];
#pragma unroll
    for (int m = 0; m < 4; ++m)
#pragma unroll
        for (int n = 0; n < 4; ++n) acc[m][n] = (f32x4){0.f, 0.f, 0.f, 0.f};

#pragma unroll
    for (int ph = 0; ph < 2; ++ph) {
        const ushort* __restrict__ W = ph ? W2 : W1;
        short8 a[4][4], b[4][4];
#pragma unroll
        for (int m = 0; m < 4; ++m)
#pragma unroll
            for (int k = 0; k < 4; ++k) {
                const int row = row0 + m * 16 + lr;
                if (ph == 0)
                    a[m][k] = *(const short8*)&AGG[(size_t)(k >> 1) * SLS + (size_t)row * 64 + (k & 1) * 32 + lk * 8];
                else
                    a[m][k] = *(const short8*)&H0[(size_t)row * HDIM + k * 32 + lk * 8];
            }
#pragma unroll
        for (int n = 0; n < 4; ++n)
#pragma unroll
            for (int k = 0; k < 4; ++k)
                b[n][k] = *(const short8*)&W[(size_t)(col0 + n * 16 + lr) * HDIM + k * 32 + lk * 8];
#pragma unroll
        for (int k = 0; k < 4; ++k)
#pragma unroll
            for (int m = 0; m < 4; ++m)
#pragma unroll
                for (int n = 0; n < 4; ++n)
                    acc[m][n] = __builtin_amdgcn_mfma_f32_16x16x32_bf16(a[m][k], b[n][k], acc[m][n], 0, 0, 0);
    }

#pragma unroll
    for (int m = 0; m < 4; ++m) {
        const int rb = row0 + m * 16 + lk * 4;
#pragma unroll
        for (int j = 0; j < 4; ++j) {
            const int row = rb + j;
#pragma unroll
            for (int n = 0; n < 4; ++n)
                H[(size_t)wn * SLS + (size_t)row * 64 + n * 16 + lr] = f2bf(fmaxf(acc[m][n][j], 0.f));
        }
    }
}

// ---------------- output GEMM + fused bias + log_softmax (A sliced) ----------------

__global__ __launch_bounds__(256) void k_gemm_out(
    const ushort* __restrict__ A, const ushort* __restrict__ W,
    const float* __restrict__ bias, float* __restrict__ out) {
    const int tid = threadIdx.x;
    const int wid = tid >> 6, l = tid & 63;
    const int lr = l & 15, lk = l >> 4;
    const int row0 = blockIdx.x * 128 + wid * 32;

    short8 a[2][4], b[4][4];
#pragma unroll
    for (int m = 0; m < 2; ++m)
#pragma unroll
        for (int k = 0; k < 4; ++k) {
            const int row = row0 + m * 16 + lr;
            a[m][k] = *(const short8*)&A[(size_t)(k >> 1) * SLS + (size_t)row * 64 + (k & 1) * 32 + lk * 8];
        }
#pragma unroll
    for (int n = 0; n < 4; ++n)
#pragma unroll
        for (int k = 0; k < 4; ++k)
            b[n][k] = *(const short8*)&W[(size_t)(n * 16 + lr) * HDIM + k * 32 + lk * 8];

    f32x4 acc[2][4];
#pragma unroll
    for (int m = 0; m < 2; ++m)
#pragma unroll
        for (int n = 0; n < 4; ++n) acc[m][n] = (f32x4){0.f, 0.f, 0.f, 0.f};
#pragma unroll
    for (int k = 0; k < 4; ++k)
#pragma unroll
        for (int m = 0; m < 2; ++m)
#pragma unroll
            for (int n = 0; n < 4; ++n)
                acc[m][n] = __builtin_amdgcn_mfma_f32_16x16x32_bf16(a[m][k], b[n][k], acc[m][n], 0, 0, 0);

    float bv[4];
#pragma unroll
    for (int n = 0; n < 4; ++n) bv[n] = bias[n * 16 + lr];

#pragma unroll
    for (int m = 0; m < 2; ++m) {
#pragma unroll
        for (int j = 0; j < 4; ++j) {
            float z[4];
#pragma unroll
            for (int n = 0; n < 4; ++n) z[n] = acc[m][n][j] + bv[n];
            float mx = fmaxf(fmaxf(z[0], z[1]), fmaxf(z[2], z[3]));
#pragma unroll
            for (int off = 1; off < 16; off <<= 1) mx = fmaxf(mx, __shfl_xor(mx, off));
            float s = 0.f;
#pragma unroll
            for (int n = 0; n < 4; ++n) s += expf(z[n] - mx);
#pragma unroll
            for (int off = 1; off < 16; off <<= 1) s += __shfl_xor(s, off);
            float lg = mx + logf(s);
            int r = row0 + m * 16 + lk * 4 + j;
            if (r < N_NODES) {
#pragma unroll
                for (int n = 0; n < 4; ++n)
                    out[(size_t)r * COUT + n * 16 + lr] = z[n] - lg;
            }
        }
    }
}

// ---------------- launch ----------------

extern "C" void kernel_launch(void* const* d_in, const int* in_sizes, int n_in,
                              void* d_out, int out_size, void* d_ws, size_t ws_size,
                              hipStream_t stream) {
    const float* x = (const float*)d_in[0];
    const int* ei = (const int*)d_in[1];
    const float* ew = (const float*)d_in[2];
    const float* w_in = (const float*)d_in[3];
    const float* b_in = (const float*)d_in[4];
    const float* ws1 = (const float*)d_in[5];
    const float* ws2 = (const float*)d_in[6];
    const float* w_out = (const float*)d_in[7];
    const float* b_out = (const float*)d_in[8];
    float* out = (float*)d_out;

    char* p = (char*)d_ws;
    auto alloc = [&](size_t bytes) {
        void* r = (void*)p;
        p += (bytes + 255) & ~(size_t)255;
        return r;
    };
    float* dinv = (float*)alloc(N_NODES * 4);     // deg -> dinv in place
    int* cnt = (int*)alloc(N_NODES * 4);
    int* ptrTmp = (int*)alloc(N_NODES * 4);
    int* bsum = (int*)alloc(256 * 4);
    int* boff = (int*)alloc(256 * 4);
    int* ptr = (int*)alloc((N_NODES + 1) * 4);
    int* rank = (int*)alloc((size_t)E_EDGES * 4);
    unsigned* spacku = (unsigned*)alloc((size_t)E_EDGES * 4);
    ushort* xb = (ushort*)alloc((size_t)N_PAD * HDIM * 2);
    ushort* h = (ushort*)alloc(2 * SLS * 2);       // sliced [2][N_PAD][64]
    ushort* h0 = (ushort*)alloc((size_t)N_PAD * HDIM * 2);
    ushort* agg_h = (ushort*)alloc(2 * SLS * 2);   // sliced
    ushort* wt_in = (ushort*)alloc(128 * 128 * 2);
    ushort* wt1 = (ushort*)alloc((size_t)NLAYERS * 128 * 128 * 2);
    ushort* wt2 = (ushort*)alloc((size_t)NLAYERS * 128 * 128 * 2);
    ushort* wt_out = (ushort*)alloc(64 * 128 * 2);

    const int ge4 = (E_EDGES / 4 + 255) / 256;  // 625
    k_init<<<SCAN_BLKS, 256, 0, stream>>>(dinv, cnt);
    k_edge<<<ge4, 256, 0, stream>>>(ei, ew, dinv, cnt, rank);
    k_dinv<<<SCAN_BLKS, 256, 0, stream>>>(dinv);
    k_scan1<<<SCAN_BLKS, 256, 0, stream>>>(cnt, ptrTmp, bsum);
    k_scan2<<<1, 256, 0, stream>>>(bsum, boff);
    k_scan3<<<SCAN_BLKS, 256, 0, stream>>>(ptrTmp, boff, ptr);
    k_scatter<<<ge4, 256, 0, stream>>>(ei, ew, dinv, ptr, rank, spacku);

    k_convert_w<<<34, 256, 0, stream>>>(w_in, ws1, ws2, w_out, wt_in, wt1, wt2, wt_out);
    k_convert_x<<<(N_PAD * (HDIM / 8) + 255) / 256, 256, 0, stream>>>(x, xb);

    const int gb = N_PAD / 128;  // 391
    k_gemm_in<<<gb, 256, 0, stream>>>(xb, wt_in, b_in, h, h0);

    const int gagg = (N_NODES + 3) / 4 * 2;  // 25000 blocks (node-group x slice)
    for (int i = 0; i < NLAYERS; ++i) {
        k_aggregate<<<gagg, 256, 0, stream>>>(h, dinv, ptr, spacku, agg_h);
        k_gemm_layer<<<gb, 256, 0, stream>>>(agg_h, h0,
                                             wt1 + (size_t)i * 16384,
                                             wt2 + (size_t)i * 16384, h);
    }

    k_gemm_out<<<gb, 256, 0, stream>>>(h, wt_out, b_out, out);
}

// Round 8
// 865.451 us; speedup vs baseline: 1.1730x; 1.1730x over previous
//
#include <hip/hip_runtime.h>
#include <cmath>
#include <cstddef>

#define N_NODES 50000
#define N_PAD   50048
#define E_EDGES 640000
#define HDIM 128
#define COUT 64
#define NLAYERS 16
#define ALPHA_C 0.1f
#define LAMDA_C 0.5f
#define SCAN_BLKS 196   // ceil(50000/256)

typedef __attribute__((ext_vector_type(8))) short short8;
typedef __attribute__((ext_vector_type(4))) float f32x4;

__device__ __forceinline__ float bf2f(ushort u) {
    union { unsigned u; float f; } x; x.u = ((unsigned)u) << 16; return x.f;
}
__device__ __forceinline__ ushort f2bf(float f) {
    union { float f; unsigned u; } x; x.f = f;
    unsigned r = x.u + 0x7FFFu + ((x.u >> 16) & 1u);
    return (ushort)(r >> 16);
}

// ---------------- graph setup ----------------

__global__ __launch_bounds__(256) void k_init(float* deg, int* cnt) {
    int i = blockIdx.x * 256 + threadIdx.x;
    if (i < N_NODES) { deg[i] = 1.0f; cnt[i] = 0; }
}

// 4 edges/thread; cnt atomicAdd return value = intra-bucket rank (kills scatter atomics)
__global__ __launch_bounds__(256) void k_edge(const int* __restrict__ ei,
                                              const float* __restrict__ ew,
                                              float* deg, int* cnt,
                                              int* __restrict__ rank) {
    int t = blockIdx.x * 256 + threadIdx.x;
    int e0 = t * 4;
    if (e0 >= E_EDGES) return;
    int4 r = *(const int4*)&ei[e0];
    int4 c = *(const int4*)&ei[E_EDGES + e0];
    float4 w = *(const float4*)&ew[e0];
    atomicAdd(&deg[r.x], w.x);
    atomicAdd(&deg[r.y], w.y);
    atomicAdd(&deg[r.z], w.z);
    atomicAdd(&deg[r.w], w.w);
    int4 rk;
    rk.x = atomicAdd(&cnt[c.x], 1);
    rk.y = atomicAdd(&cnt[c.y], 1);
    rk.z = atomicAdd(&cnt[c.z], 1);
    rk.w = atomicAdd(&cnt[c.w], 1);
    *(int4*)&rank[e0] = rk;
}

__global__ __launch_bounds__(256) void k_dinv(float* deg) {
    int i = blockIdx.x * 256 + threadIdx.x;
    if (i < N_NODES) deg[i] = 1.0f / sqrtf(deg[i]);
}

__global__ __launch_bounds__(256) void k_scan1(const int* __restrict__ cnt,
                                               int* ptrTmp, int* bsum) {
    __shared__ int s[256];
    int t = threadIdx.x;
    int i = blockIdx.x * 256 + t;
    int v = (i < N_NODES) ? cnt[i] : 0;
    s[t] = v; __syncthreads();
    for (int off = 1; off < 256; off <<= 1) {
        int x = s[t]; int y = (t >= off) ? s[t - off] : 0;
        __syncthreads();
        s[t] = x + y; __syncthreads();
    }
    if (i < N_NODES) ptrTmp[i] = s[t] - v;
    if (t == 255) bsum[blockIdx.x] = s[255];
}

__global__ __launch_bounds__(256) void k_scan2(const int* __restrict__ bsum, int* boff) {
    __shared__ int s[256];
    int t = threadIdx.x;
    int v = (t < SCAN_BLKS) ? bsum[t] : 0;
    s[t] = v; __syncthreads();
    for (int off = 1; off < 256; off <<= 1) {
        int x = s[t]; int y = (t >= off) ? s[t - off] : 0;
        __syncthreads();
        s[t] = x + y; __syncthreads();
    }
    if (t < SCAN_BLKS) boff[t] = s[t] - v;
}

__global__ __launch_bounds__(256) void k_scan3(const int* __restrict__ ptrTmp,
                                               const int* __restrict__ boff, int* ptr) {
    int i = blockIdx.x * 256 + threadIdx.x;
    if (i < N_NODES) ptr[i] = ptrTmp[i] + boff[blockIdx.x];
    if (i == 0) ptr[N_NODES] = E_EDGES;
}

// atomic-free scatter: pos = ptr[c] + rank[e]; meta packed (row<<16 | bf16(norm))
__global__ __launch_bounds__(256) void k_scatter(const int* __restrict__ ei,
                                                 const float* __restrict__ ew,
                                                 const float* __restrict__ dinv,
                                                 const int* __restrict__ ptr,
                                                 const int* __restrict__ rank,
                                                 unsigned* __restrict__ spacku) {
    int t = blockIdx.x * 256 + threadIdx.x;
    int e0 = t * 4;
    if (e0 >= E_EDGES) return;
    int4 r = *(const int4*)&ei[e0];
    int4 c = *(const int4*)&ei[E_EDGES + e0];
    float4 w = *(const float4*)&ew[e0];
    int4 rk = *(const int4*)&rank[e0];
#pragma unroll
    for (int j = 0; j < 4; ++j) {
        int rr = (j == 0) ? r.x : (j == 1) ? r.y : (j == 2) ? r.z : r.w;
        int cc = (j == 0) ? c.x : (j == 1) ? c.y : (j == 2) ? c.z : c.w;
        float wwv = (j == 0) ? w.x : (j == 1) ? w.y : (j == 2) ? w.z : w.w;
        int rkj = (j == 0) ? rk.x : (j == 1) ? rk.y : (j == 2) ? rk.z : rk.w;
        int pos = ptr[cc] + rkj;
        float nm = dinv[rr] * wwv * dinv[cc];
        spacku[pos] = ((unsigned)rr << 16) | (unsigned)f2bf(nm);
    }
}

// ---------------- weight convert + transpose + residual fold ----------------
// layer weights become W' = beta*W + diagC*I, stored bf16 transposed [C][R]

__global__ __launch_bounds__(256) void k_convert_w(
    const float* __restrict__ w_in, const float* __restrict__ ws1,
    const float* __restrict__ ws2, const float* __restrict__ w_out,
    ushort* wt_in, ushort* wt1, ushort* wt2, ushort* wt_out) {
    __shared__ float tile[128][129];
    int b = blockIdx.x;
    const float* src; ushort* dst; int R = 128, C = 128;
    float scale = 1.f, diag = 0.f;
    if (b == 0) { src = w_in; dst = wt_in; }
    else if (b <= 16) {
        int i = b - 1;
        float beta = logf(LAMDA_C / (float)(i + 1) + 1.0f);
        scale = beta; diag = (1.f - beta) * (1.f - ALPHA_C);
        src = ws1 + (size_t)i * 16384; dst = wt1 + (size_t)i * 16384;
    } else if (b <= 32) {
        int i = b - 17;
        float beta = logf(LAMDA_C / (float)(i + 1) + 1.0f);
        scale = beta; diag = (1.f - beta) * ALPHA_C;
        src = ws2 + (size_t)i * 16384; dst = wt2 + (size_t)i * 16384;
    } else { src = w_out; dst = wt_out; C = 64; }
    for (int idx = threadIdx.x; idx < R * C; idx += 256) {
        int k = idx / C, n = idx % C;
        tile[k][n] = src[idx] * scale + ((k == n) ? diag : 0.f);
    }
    __syncthreads();
    for (int idx = threadIdx.x; idx < R * C; idx += 256) {
        int n = idx / R, k = idx % R;
        dst[idx] = f2bf(tile[k][n]);
    }
}

// ---------------- x convert (f32 -> bf16, zero-pad rows) ----------------

__global__ __launch_bounds__(256) void k_convert_x(const float* __restrict__ x,
                                                   ushort* __restrict__ xb) {
    int c8 = blockIdx.x * 256 + threadIdx.x;
    if (c8 >= N_PAD * (HDIM / 8)) return;
    int row = c8 / (HDIM / 8);
    short8 o;
    if (row < N_NODES) {
        const float4 f0 = *(const float4*)&x[(size_t)c8 * 8];
        const float4 f1 = *(const float4*)&x[(size_t)c8 * 8 + 4];
        o[0] = (short)f2bf(f0.x); o[1] = (short)f2bf(f0.y);
        o[2] = (short)f2bf(f0.z); o[3] = (short)f2bf(f0.w);
        o[4] = (short)f2bf(f1.x); o[5] = (short)f2bf(f1.y);
        o[6] = (short)f2bf(f1.z); o[7] = (short)f2bf(f1.w);
    } else {
        o = (short8){0, 0, 0, 0, 0, 0, 0, 0};
    }
    *(short8*)&xb[(size_t)c8 * 8] = o;
}

// ---------------- input GEMM: h = h0 = relu(xb @ W + bias) ----------------

__global__ __launch_bounds__(256) void k_gemm_in(
    const ushort* __restrict__ A, const ushort* __restrict__ W,
    const float* __restrict__ bias, ushort* __restrict__ O0, ushort* __restrict__ O1) {
    const int tid = threadIdx.x;
    const int wid = tid >> 6, l = tid & 63;
    const int wm = wid >> 1, wn = wid & 1;
    const int lr = l & 15, lk = l >> 4;
    const int row0 = blockIdx.x * 128 + wm * 64;
    const int col0 = wn * 64;

    short8 a[4][4], b[4][4];
#pragma unroll
    for (int m = 0; m < 4; ++m)
#pragma unroll
        for (int k = 0; k < 4; ++k)
            a[m][k] = *(const short8*)&A[(size_t)(row0 + m * 16 + lr) * HDIM + k * 32 + lk * 8];
#pragma unroll
    for (int n = 0; n < 4; ++n)
#pragma unroll
        for (int k = 0; k < 4; ++k)
            b[n][k] = *(const short8*)&W[(size_t)(col0 + n * 16 + lr) * HDIM + k * 32 + lk * 8];

    f32x4 acc[4][4];
#pragma unroll
    for (int m = 0; m < 4; ++m)
#pragma unroll
        for (int n = 0; n < 4; ++n) acc[m][n] = (f32x4){0.f, 0.f, 0.f, 0.f};
#pragma unroll
    for (int k = 0; k < 4; ++k)
#pragma unroll
        for (int m = 0; m < 4; ++m)
#pragma unroll
            for (int n = 0; n < 4; ++n)
                acc[m][n] = __builtin_amdgcn_mfma_f32_16x16x32_bf16(a[m][k], b[n][k], acc[m][n], 0, 0, 0);

    float bv[4];
#pragma unroll
    for (int n = 0; n < 4; ++n) bv[n] = bias[col0 + n * 16 + lr];
#pragma unroll
    for (int m = 0; m < 4; ++m) {
        const int rb = row0 + m * 16 + lk * 4;
#pragma unroll
        for (int j = 0; j < 4; ++j) {
            const size_t ro = (size_t)(rb + j) * HDIM;
#pragma unroll
            for (int n = 0; n < 4; ++n) {
                const int c = col0 + n * 16 + lr;
                float v = fmaxf(acc[m][n][j] + bv[n], 0.f);
                ushort u = f2bf(v);
                O0[ro + c] = u;
                O1[ro + c] = u;
            }
        }
    }
}

// ---------------- aggregation: agg_h = A_hat * h ----------------
// wave per node; quarter-wave (16 lanes x ushort8 = 256B row) per edge;
// 8 edges in flight (2x unroll); branch-free (padded lanes carry meta=0).
// Shuffle idx safety: j steps by 8, j <= 56, so j+4+q <= 63 (no wrap).

__global__ __launch_bounds__(256) void k_aggregate(
    const ushort* __restrict__ h, const float* __restrict__ dinv,
    const int* __restrict__ ptr, const unsigned* __restrict__ spacku,
    ushort* __restrict__ agg_h) {
    const int v = blockIdx.x * 4 + (threadIdx.x >> 6);
    const int l = threadIdx.x & 63;
    const int q = l >> 4, i = l & 15;
    if (v >= N_NODES) return;
    const int beg = ptr[v], end = ptr[v + 1];

    float acc[8];
#pragma unroll
    for (int d = 0; d < 8; ++d) acc[d] = 0.f;

    for (int base = beg; base < end; base += 64) {
        const int cnt = min(64, end - base);
        unsigned meta = 0;
        if (base + l < end) meta = spacku[base + l];
        for (int j = 0; j < cnt; j += 8) {
            unsigned mu0 = (unsigned)__shfl((int)meta, j + q);
            unsigned mu1 = (unsigned)__shfl((int)meta, j + 4 + q);
            int rr0 = (int)(mu0 >> 16);
            int rr1 = (int)(mu1 >> 16);
            short8 sv0 = *(const short8*)&h[(size_t)rr0 * HDIM + i * 8];
            short8 sv1 = *(const short8*)&h[(size_t)rr1 * HDIM + i * 8];
            float nn0 = bf2f((ushort)(mu0 & 0xFFFFu));
            float nn1 = bf2f((ushort)(mu1 & 0xFFFFu));
#pragma unroll
            for (int d = 0; d < 8; ++d)
                acc[d] = fmaf(nn0, bf2f((ushort)sv0[d]), acc[d]);
#pragma unroll
            for (int d = 0; d < 8; ++d)
                acc[d] = fmaf(nn1, bf2f((ushort)sv1[d]), acc[d]);
        }
    }
#pragma unroll
    for (int d = 0; d < 8; ++d) {
        acc[d] += __shfl_xor(acc[d], 16);
        acc[d] += __shfl_xor(acc[d], 32);
    }
    if (q == 0) {
        const float dv = dinv[v];
        const float dv2 = dv * dv;
        short8 s0 = *(const short8*)&h[(size_t)v * HDIM + i * 8];
        short8 o;
#pragma unroll
        for (int d = 0; d < 8; ++d)
            o[d] = (short)f2bf(acc[d] + dv2 * bf2f((ushort)s0[d]));
        *(short8*)&agg_h[(size_t)v * HDIM + i * 8] = o;
    }
}

// ---------------- layer GEMM: h = relu(agg_h @ W1' + h0 @ W2') ----------------
// residuals folded into W1'/W2' diagonals; two K=128 phases accumulate into acc.

__global__ __launch_bounds__(256) void k_gemm_layer(
    const ushort* __restrict__ AGG, const ushort* __restrict__ H0,
    const ushort* __restrict__ W1, const ushort* __restrict__ W2,
    ushort* __restrict__ H) {
    const int tid = threadIdx.x;
    const int wid = tid >> 6, l = tid & 63;
    const int wm = wid >> 1, wn = wid & 1;
    const int lr = l & 15, lk = l >> 4;
    const int row0 = blockIdx.x * 128 + wm * 64;
    const int col0 = wn * 64;

    f32x4 acc[4][4];
#pragma unroll
    for (int m = 0; m < 4; ++m)
#pragma unroll
        for (int n = 0; n < 4; ++n) acc[m][n] = (f32x4){0.f, 0.f, 0.f, 0.f};

#pragma unroll
    for (int ph = 0; ph < 2; ++ph) {
        const ushort* __restrict__ A = ph ? H0 : AGG;
        const ushort* __restrict__ W = ph ? W2 : W1;
        short8 a[4][4], b[4][4];
#pragma unroll
        for (int m = 0; m < 4; ++m)
#pragma unroll
            for (int k = 0; k < 4; ++k)
                a[m][k] = *(const short8*)&A[(size_t)(row0 + m * 16 + lr) * HDIM + k * 32 + lk * 8];
#pragma unroll
        for (int n = 0; n < 4; ++n)
#pragma unroll
            for (int k = 0; k < 4; ++k)
                b[n][k] = *(const short8*)&W[(size_t)(col0 + n * 16 + lr) * HDIM + k * 32 + lk * 8];
#pragma unroll
        for (int k = 0; k < 4; ++k)
#pragma unroll
            for (int m = 0; m < 4; ++m)
#pragma unroll
                for (int n = 0; n < 4; ++n)
                    acc[m][n] = __builtin_amdgcn_mfma_f32_16x16x32_bf16(a[m][k], b[n][k], acc[m][n], 0, 0, 0);
    }

#pragma unroll
    for (int m = 0; m < 4; ++m) {
        const int rb = row0 + m * 16 + lk * 4;
#pragma unroll
        for (int j = 0; j < 4; ++j) {
            const size_t ro = (size_t)(rb + j) * HDIM;
#pragma unroll
            for (int n = 0; n < 4; ++n)
                H[ro + col0 + n * 16 + lr] = f2bf(fmaxf(acc[m][n][j], 0.f));
        }
    }
}

// ---------------- output GEMM + fused bias + log_softmax ----------------

__global__ __launch_bounds__(256) void k_gemm_out(
    const ushort* __restrict__ A, const ushort* __restrict__ W,
    const float* __restrict__ bias, float* __restrict__ out) {
    const int tid = threadIdx.x;
    const int wid = tid >> 6, l = tid & 63;
    const int lr = l & 15, lk = l >> 4;
    const int row0 = blockIdx.x * 128 + wid * 32;

    short8 a[2][4], b[4][4];
#pragma unroll
    for (int m = 0; m < 2; ++m)
#pragma unroll
        for (int k = 0; k < 4; ++k)
            a[m][k] = *(const short8*)&A[(size_t)(row0 + m * 16 + lr) * HDIM + k * 32 + lk * 8];
#pragma unroll
    for (int n = 0; n < 4; ++n)
#pragma unroll
        for (int k = 0; k < 4; ++k)
            b[n][k] = *(const short8*)&W[(size_t)(n * 16 + lr) * HDIM + k * 32 + lk * 8];

    f32x4 acc[2][4];
#pragma unroll
    for (int m = 0; m < 2; ++m)
#pragma unroll
        for (int n = 0; n < 4; ++n) acc[m][n] = (f32x4){0.f, 0.f, 0.f, 0.f};
#pragma unroll
    for (int k = 0; k < 4; ++k)
#pragma unroll
        for (int m = 0; m < 2; ++m)
#pragma unroll
            for (int n = 0; n < 4; ++n)
                acc[m][n] = __builtin_amdgcn_mfma_f32_16x16x32_bf16(a[m][k], b[n][k], acc[m][n], 0, 0, 0);

    float bv[4];
#pragma unroll
    for (int n = 0; n < 4; ++n) bv[n] = bias[n * 16 + lr];

#pragma unroll
    for (int m = 0; m < 2; ++m) {
#pragma unroll
        for (int j = 0; j < 4; ++j) {
            float z[4];
#pragma unroll
            for (int n = 0; n < 4; ++n) z[n] = acc[m][n][j] + bv[n];
            float mx = fmaxf(fmaxf(z[0], z[1]), fmaxf(z[2], z[3]));
#pragma unroll
            for (int off = 1; off < 16; off <<= 1) mx = fmaxf(mx, __shfl_xor(mx, off));
            float s = 0.f;
#pragma unroll
            for (int n = 0; n < 4; ++n) s += expf(z[n] - mx);
#pragma unroll
            for (int off = 1; off < 16; off <<= 1) s += __shfl_xor(s, off);
            float lg = mx + logf(s);
            int r = row0 + m * 16 + lk * 4 + j;
            if (r < N_NODES) {
#pragma unroll
                for (int n = 0; n < 4; ++n)
                    out[(size_t)r * COUT + n * 16 + lr] = z[n] - lg;
            }
        }
    }
}

// ---------------- launch ----------------

extern "C" void kernel_launch(void* const* d_in, const int* in_sizes, int n_in,
                              void* d_out, int out_size, void* d_ws, size_t ws_size,
                              hipStream_t stream) {
    const float* x = (const float*)d_in[0];
    const int* ei = (const int*)d_in[1];
    const float* ew = (const float*)d_in[2];
    const float* w_in = (const float*)d_in[3];
    const float* b_in = (const float*)d_in[4];
    const float* ws1 = (const float*)d_in[5];
    const float* ws2 = (const float*)d_in[6];
    const float* w_out = (const float*)d_in[7];
    const float* b_out = (const float*)d_in[8];
    float* out = (float*)d_out;

    char* p = (char*)d_ws;
    auto alloc = [&](size_t bytes) {
        void* r = (void*)p;
        p += (bytes + 255) & ~(size_t)255;
        return r;
    };
    float* dinv = (float*)alloc(N_NODES * 4);     // deg -> dinv in place
    int* cnt = (int*)alloc(N_NODES * 4);
    int* ptrTmp = (int*)alloc(N_NODES * 4);
    int* bsum = (int*)alloc(256 * 4);
    int* boff = (int*)alloc(256 * 4);
    int* ptr = (int*)alloc((N_NODES + 1) * 4);
    int* rank = (int*)alloc((size_t)E_EDGES * 4);
    unsigned* spacku = (unsigned*)alloc((size_t)E_EDGES * 4);
    ushort* xb = (ushort*)alloc((size_t)N_PAD * HDIM * 2);
    ushort* h = (ushort*)alloc((size_t)N_PAD * HDIM * 2);
    ushort* h0 = (ushort*)alloc((size_t)N_PAD * HDIM * 2);
    ushort* agg_h = (ushort*)alloc((size_t)N_PAD * HDIM * 2);
    ushort* wt_in = (ushort*)alloc(128 * 128 * 2);
    ushort* wt1 = (ushort*)alloc((size_t)NLAYERS * 128 * 128 * 2);
    ushort* wt2 = (ushort*)alloc((size_t)NLAYERS * 128 * 128 * 2);
    ushort* wt_out = (ushort*)alloc(64 * 128 * 2);

    const int ge4 = (E_EDGES / 4 + 255) / 256;  // 625
    k_init<<<SCAN_BLKS, 256, 0, stream>>>(dinv, cnt);
    k_edge<<<ge4, 256, 0, stream>>>(ei, ew, dinv, cnt, rank);
    k_dinv<<<SCAN_BLKS, 256, 0, stream>>>(dinv);
    k_scan1<<<SCAN_BLKS, 256, 0, stream>>>(cnt, ptrTmp, bsum);
    k_scan2<<<1, 256, 0, stream>>>(bsum, boff);
    k_scan3<<<SCAN_BLKS, 256, 0, stream>>>(ptrTmp, boff, ptr);
    k_scatter<<<ge4, 256, 0, stream>>>(ei, ew, dinv, ptr, rank, spacku);

    k_convert_w<<<34, 256, 0, stream>>>(w_in, ws1, ws2, w_out, wt_in, wt1, wt2, wt_out);
    k_convert_x<<<(N_PAD * (HDIM / 8) + 255) / 256, 256, 0, stream>>>(x, xb);

    const int gb = N_PAD / 128;  // 391
    k_gemm_in<<<gb, 256, 0, stream>>>(xb, wt_in, b_in, h, h0);

    for (int i = 0; i < NLAYERS; ++i) {
        k_aggregate<<<(N_NODES + 3) / 4, 256, 0, stream>>>(h, dinv, ptr, spacku, agg_h);
        k_gemm_layer<<<gb, 256, 0, stream>>>(agg_h, h0,
                                             wt1 + (size_t)i * 16384,
                                             wt2 + (size_t)i * 16384, h);
    }

    k_gemm_out<<<gb, 256, 0, stream>>>(h, wt_out, b_out, out);
}